// Round 11
// baseline (398.243 us; speedup 1.0000x reference)
//
#include <hip/hip_runtime.h>
#include <hip/hip_bf16.h>

#define N_NODES 50000
#define N_EDGES 800000
#define IN_CH 256
#define HID 256
#define OUT_CH 128
#define N_GRAPHS 64
#define SCAN_BLOCKS 196     // ceil(50001/256)
#define M_PAD 50048         // 391 * 128
#define POOL_CHUNK 32
#define POOL_BLOCKS ((N_NODES + POOL_CHUNK - 1) / POOL_CHUNK)   // 1563
#define COUNT_BLOCKS 3125   // N_EDGES / 256
#define CVTX_BLOCKS  12512  // M_PAD*64 / 256
#define GEMM1_BLOCKS 782    // 391 * 2

typedef __bf16 bf16x8 __attribute__((ext_vector_type(8)));
typedef float f32x4 __attribute__((ext_vector_type(4)));

// bf16 <-> f32 helpers (RNE on pack)
__device__ __forceinline__ float bf2f(unsigned short u) {
    union { unsigned int i; float f; } x; x.i = ((unsigned int)u) << 16; return x.f;
}
__device__ __forceinline__ unsigned short f2bf(float f) {
    union { float f; unsigned int i; } x; x.f = f;
    unsigned int r = x.i + 0x7FFFu + ((x.i >> 16) & 1u);
    return (unsigned short)(r >> 16);
}

__device__ __forceinline__ void load16(const void* g, void* l) {
    __builtin_amdgcn_global_load_lds(
        (const __attribute__((address_space(1))) void*)g,
        (__attribute__((address_space(3))) void*)l, 16, 0, 0);
}

// final rowptr = block-local exclusive + per-256-chunk offset
__device__ __forceinline__ int rp(const int* __restrict__ rl,
                                  const int* __restrict__ boff, int i) {
    return rl[i] + boff[i >> 8];
}

// ---------------------------------------------------------------------------
// Launch A: histogram of dst (blocks 0..3124) + x f32->bf16 padded convert
// (blocks 3125..15636). Independent subgraphs overlapped in one dispatch.
// ---------------------------------------------------------------------------
__global__ __launch_bounds__(256) void count_cvtx_kernel(const int* __restrict__ ei,
                                                         int* __restrict__ cnt,
                                                         const float* __restrict__ x,
                                                         unsigned short* __restrict__ xb) {
    int b = blockIdx.x;
    if (b < COUNT_BLOCKS) {
        int e = b * 256 + threadIdx.x;
        atomicAdd(&cnt[ei[N_EDGES + e]], 1);
        return;
    }
    int i = (b - COUNT_BLOCKS) * 256 + threadIdx.x;    // float4 index
    ushort4 o;
    if (i < N_NODES * (IN_CH / 4)) {
        float4 v = ((const float4*)x)[i];
        o.x = f2bf(v.x); o.y = f2bf(v.y); o.z = f2bf(v.z); o.w = f2bf(v.w);
    } else {
        o = make_ushort4(0, 0, 0, 0);
    }
    ((ushort4*)xb)[i] = o;
}

// ---------------------------------------------------------------------------
// scan_a: block-local exclusive scan; emits dinv/invdeg; zeroes fillp.
// ---------------------------------------------------------------------------
__global__ __launch_bounds__(256) void scan_a_kernel(const int* __restrict__ cnt,
                                                     int* __restrict__ rl,
                                                     int* __restrict__ blocksum,
                                                     float* __restrict__ dinv,
                                                     float* __restrict__ invdeg,
                                                     int* __restrict__ fillp) {
    __shared__ int tmp[256];
    int t = threadIdx.x;
    int i = blockIdx.x * 256 + t;
    int v = (i < N_NODES) ? cnt[i] : 0;
    int x = v;
    tmp[t] = x;
    __syncthreads();
#pragma unroll
    for (int off = 1; off < 256; off <<= 1) {
        int y = (t >= off) ? tmp[t - off] : 0;
        __syncthreads();
        x += y;
        tmp[t] = x;
        __syncthreads();
    }
    if (i <= N_NODES) rl[i] = x - v;
    if (i < N_NODES) {
        float d = (float)v + 1.0f;         // +1 self loop
        dinv[i] = rsqrtf(d);
        invdeg[i] = 1.0f / d;
        fillp[i] = 0;
    }
    if (t == 255) blocksum[blockIdx.x] = x;
}

// ---------------------------------------------------------------------------
// blocks 0..383: W1/W2 f32 -> bf16 transposed [N][K].
// block 384: scan of block sums -> blockoff, plus zero gcnt/pool/done.
// ---------------------------------------------------------------------------
__global__ __launch_bounds__(256) void scanb_cvtw_kernel(
        const int* __restrict__ blocksum, int* __restrict__ blockoff,
        const float* __restrict__ W1, const float* __restrict__ W2,
        unsigned short* __restrict__ w1t, unsigned short* __restrict__ w2t,
        float* __restrict__ zbase /* gcnt(64)+pool(8192)+done(1) */) {
    int t = threadIdx.x;
    if (blockIdx.x < 384) {
        int i = blockIdx.x * 256 + t;                 // 0 .. 98303
        if (i < HID * IN_CH) {                        // W1t[n][k] = W1[k][n]
            int n = i >> 8, k = i & 255;
            w1t[i] = f2bf(W1[k * HID + n]);
        } else {                                      // W2t[n][k] = W2[k][n]
            int j = i - HID * IN_CH;
            int n = j >> 8, k = j & 255;
            w2t[j] = f2bf(W2[k * OUT_CH + n]);
        }
        return;
    }
    for (int i = t; i < N_GRAPHS + N_GRAPHS * OUT_CH + 1; i += 256)
        zbase[i] = 0.f;
    __shared__ int tmp[256];
    int v = (t < SCAN_BLOCKS) ? blocksum[t] : 0;
    int x = v;
    tmp[t] = x;
    __syncthreads();
#pragma unroll
    for (int off = 1; off < 256; off <<= 1) {
        int y = (t >= off) ? tmp[t - off] : 0;
        __syncthreads();
        x += y;
        tmp[t] = x;
        __syncthreads();
    }
    if (t < SCAN_BLOCKS) blockoff[t] = x - v;
}

// ---------------------------------------------------------------------------
// Launch B (after scanb): gemm1 tiles (blocks 0..781) + CSR fill (rest).
// Both depend only on scanb_cvtw. gemm first so MFMA blocks start early.
// ---------------------------------------------------------------------------
__device__ __forceinline__ void gemm_body(const unsigned short* __restrict__ A,
                                          const unsigned short* __restrict__ Bt,
                                          unsigned short* __restrict__ C,
                                          int N, int bxx, int byy, char* As, char* Bs) {
    const int K = 256;
    int tid = threadIdx.x;
    int bm = bxx * 128;
    int bn = byy * 128;
    int lane = tid & 63, wave = tid >> 6;
    int lane15 = lane & 15, quad = lane >> 4;
    int wm0 = (wave >> 1) << 6;
    int wn0 = (wave & 1) << 6;

    int s1 = tid, s2 = tid + 256;
    int r1 = s1 >> 2, q1 = (s1 & 3) ^ ((r1 >> 1) & 3);
    int r2 = s2 >> 2, q2 = (s2 & 3) ^ ((r2 >> 1) & 3);
    const char* gA1 = (const char*)(A + (size_t)(bm + r1) * K) + (q1 << 4);
    const char* gA2 = (const char*)(A + (size_t)(bm + r2) * K) + (q2 << 4);
    const char* gB1 = (const char*)(Bt + (size_t)(bn + r1) * K) + (q1 << 4);
    const char* gB2 = (const char*)(Bt + (size_t)(bn + r2) * K) + (q2 << 4);
    char* lA1 = As + (wave << 10);
    char* lA2 = As + 4096 + (wave << 10);
    char* lB1 = Bs + (wave << 10);
    char* lB2 = Bs + 4096 + (wave << 10);

    int swm = (lane15 >> 1) & 3;
    f32x4 acc[4][4];
#pragma unroll
    for (int mt = 0; mt < 4; mt++)
#pragma unroll
        for (int nt = 0; nt < 4; nt++)
            acc[mt][nt] = (f32x4){0.f, 0.f, 0.f, 0.f};

    for (int k0 = 0; k0 < K; k0 += 32) {
        __syncthreads();
        load16(gA1 + (k0 << 1), lA1);
        load16(gA2 + (k0 << 1), lA2);
        load16(gB1 + (k0 << 1), lB1);
        load16(gB2 + (k0 << 1), lB2);
        __syncthreads();
        bf16x8 af[4], bfr[4];
#pragma unroll
        for (int t = 0; t < 4; t++) {
            int ra = wm0 + t * 16 + lane15;
            af[t] = *(const bf16x8*)(As + ra * 64 + ((quad ^ swm) << 4));
            int rb = wn0 + t * 16 + lane15;
            bfr[t] = *(const bf16x8*)(Bs + rb * 64 + ((quad ^ swm) << 4));
        }
#pragma unroll
        for (int mt = 0; mt < 4; mt++)
#pragma unroll
            for (int nt = 0; nt < 4; nt++)
                acc[mt][nt] = __builtin_amdgcn_mfma_f32_16x16x32_bf16(
                    af[mt], bfr[nt], acc[mt][nt], 0, 0, 0);
    }

#pragma unroll
    for (int mt = 0; mt < 4; mt++) {
        int rowb = bm + wm0 + mt * 16 + quad * 4;
#pragma unroll
        for (int nt = 0; nt < 4; nt++) {
            int col = bn + wn0 + nt * 16 + lane15;
            f32x4 a = acc[mt][nt];
            C[(size_t)(rowb + 0) * N + col] = f2bf(a[0]);
            C[(size_t)(rowb + 1) * N + col] = f2bf(a[1]);
            C[(size_t)(rowb + 2) * N + col] = f2bf(a[2]);
            C[(size_t)(rowb + 3) * N + col] = f2bf(a[3]);
        }
    }
}

__global__ __launch_bounds__(256) void fill_gemm1_kernel(
        const int* __restrict__ ei,
        const int* __restrict__ rl,
        const int* __restrict__ boff,
        int* __restrict__ fillp,
        int2* __restrict__ edge2,
        const float* __restrict__ dinv,
        const unsigned short* __restrict__ xb,
        const unsigned short* __restrict__ w1t,
        unsigned short* __restrict__ h1b) {
    __shared__ char As[8192];
    __shared__ char Bs[8192];
    int b = blockIdx.x;
    if (b < GEMM1_BLOCKS) {
        gemm_body(xb, w1t, h1b, HID, b % 391, b / 391, As, Bs);
        return;
    }
    int e = (b - GEMM1_BLOCKS) * 256 + threadIdx.x;
    if (e >= N_EDGES) return;
    int s = ei[e];
    int d = ei[N_EDGES + e];
    int p = rp(rl, boff, d) + atomicAdd(&fillp[d], 1);
    float w = dinv[s] * dinv[d];
    edge2[p] = make_int2(s, __float_as_int(w));
}

// standalone gemm for conv2
__global__ __launch_bounds__(256) void gemm_mfma_kernel(
        const unsigned short* __restrict__ A,
        const unsigned short* __restrict__ Bt,
        unsigned short* __restrict__ C,
        int N) {
    __shared__ char As[8192];
    __shared__ char Bs[8192];
    gemm_body(A, Bt, C, N, blockIdx.x, blockIdx.y, As, Bs);
}

// ---------------------------------------------------------------------------
// GCN aggregation, 256ch (conv1): wave/node, lane = 4ch, bf16 ushort4
// gathers (512B/wave — measured better than 2x256B planar), 8-edge unroll,
// f32 accumulate, ELU, bf16 output.
// ---------------------------------------------------------------------------
#define ACC4(V, W) \
    acc.x += bf2f(V.x) * W; acc.y += bf2f(V.y) * W; \
    acc.z += bf2f(V.z) * W; acc.w += bf2f(V.w) * W;

__global__ __launch_bounds__(256) void agg1_kernel(const unsigned short* __restrict__ h,
                                                   const float* __restrict__ bias,
                                                   const int* __restrict__ rl,
                                                   const int* __restrict__ boff,
                                                   const int2* __restrict__ edge2,
                                                   const float* __restrict__ invdeg,
                                                   unsigned short* __restrict__ out) {
    int node = blockIdx.x * 4 + (threadIdx.x >> 6);
    if (node >= N_NODES) return;
    int lane = threadIdx.x & 63;
    const ushort4* h4 = (const ushort4*)h;
    float id = invdeg[node];
    ushort4 sv = h4[(size_t)node * 64 + lane];
    float4 acc = make_float4(bf2f(sv.x) * id, bf2f(sv.y) * id,
                             bf2f(sv.z) * id, bf2f(sv.w) * id);
    int e0 = rp(rl, boff, node);
    int e1 = rp(rl, boff, node + 1);
    int e = e0;
    for (; e + 7 < e1; e += 8) {
        int2 ed[8];
        ushort4 v[8];
#pragma unroll
        for (int j = 0; j < 8; j++) ed[j] = edge2[e + j];
#pragma unroll
        for (int j = 0; j < 8; j++) v[j] = h4[(size_t)ed[j].x * 64 + lane];
#pragma unroll
        for (int j = 0; j < 8; j++) {
            float w = __int_as_float(ed[j].y);
            ACC4(v[j], w);
        }
    }
    for (; e + 3 < e1; e += 4) {
        int2 ed[4];
        ushort4 v[4];
#pragma unroll
        for (int j = 0; j < 4; j++) ed[j] = edge2[e + j];
#pragma unroll
        for (int j = 0; j < 4; j++) v[j] = h4[(size_t)ed[j].x * 64 + lane];
#pragma unroll
        for (int j = 0; j < 4; j++) {
            float w = __int_as_float(ed[j].y);
            ACC4(v[j], w);
        }
    }
    for (; e < e1; e++) {
        int2 ed0 = edge2[e];
        float w0 = __int_as_float(ed0.y);
        ushort4 v0 = h4[(size_t)ed0.x * 64 + lane];
        ACC4(v0, w0);
    }
    float4 bb = ((const float4*)bias)[lane];
    acc.x += bb.x; acc.y += bb.y; acc.z += bb.z; acc.w += bb.w;
    acc.x = acc.x > 0.f ? acc.x : expm1f(acc.x);
    acc.y = acc.y > 0.f ? acc.y : expm1f(acc.y);
    acc.z = acc.z > 0.f ? acc.z : expm1f(acc.z);
    acc.w = acc.w > 0.f ? acc.w : expm1f(acc.w);
    ushort4 o;
    o.x = f2bf(acc.x); o.y = f2bf(acc.y); o.z = f2bf(acc.z); o.w = f2bf(acc.w);
    ((ushort4*)out)[(size_t)node * 64 + lane] = o;
}

// 128ch (conv2): wave/node, lane = 2ch, 8-edge unroll, bf16 output.
#define ACC2(V, W) \
    acc.x += bf2f(V.x) * W; acc.y += bf2f(V.y) * W;

__global__ __launch_bounds__(256) void agg2_kernel(const unsigned short* __restrict__ h,
                                                   const float* __restrict__ bias,
                                                   const int* __restrict__ rl,
                                                   const int* __restrict__ boff,
                                                   const int2* __restrict__ edge2,
                                                   const float* __restrict__ invdeg,
                                                   unsigned short* __restrict__ out) {
    int node = blockIdx.x * 4 + (threadIdx.x >> 6);
    if (node >= N_NODES) return;
    int lane = threadIdx.x & 63;
    const ushort2* h2 = (const ushort2*)h;
    float id = invdeg[node];
    ushort2 sv = h2[(size_t)node * 64 + lane];
    float2 acc = make_float2(bf2f(sv.x) * id, bf2f(sv.y) * id);
    int e0 = rp(rl, boff, node);
    int e1 = rp(rl, boff, node + 1);
    int e = e0;
    for (; e + 7 < e1; e += 8) {
        int2 ed[8];
        ushort2 v[8];
#pragma unroll
        for (int j = 0; j < 8; j++) ed[j] = edge2[e + j];
#pragma unroll
        for (int j = 0; j < 8; j++) v[j] = h2[(size_t)ed[j].x * 64 + lane];
#pragma unroll
        for (int j = 0; j < 8; j++) {
            float w = __int_as_float(ed[j].y);
            ACC2(v[j], w);
        }
    }
    for (; e + 3 < e1; e += 4) {
        int2 ed[4];
        ushort2 v[4];
#pragma unroll
        for (int j = 0; j < 4; j++) ed[j] = edge2[e + j];
#pragma unroll
        for (int j = 0; j < 4; j++) v[j] = h2[(size_t)ed[j].x * 64 + lane];
#pragma unroll
        for (int j = 0; j < 4; j++) {
            float w = __int_as_float(ed[j].y);
            ACC2(v[j], w);
        }
    }
    for (; e < e1; e++) {
        int2 ed0 = edge2[e];
        float w0 = __int_as_float(ed0.y);
        ushort2 v0 = h2[(size_t)ed0.x * 64 + lane];
        ACC2(v0, w0);
    }
    float2 bb = ((const float2*)bias)[lane];
    acc.x += bb.x; acc.y += bb.y;
    ushort2 o;
    o.x = f2bf(acc.x); o.y = f2bf(acc.y);
    ((ushort2*)out)[(size_t)node * 64 + lane] = o;
}

// ---------------------------------------------------------------------------
// pool + final fused: run-length accumulate per 32-node chunk; the LAST
// block (device-scope done-counter) computes out = pool/gcnt using
// atomicAdd(p, 0) RMW-reads (cross-XCD-safe).
// ---------------------------------------------------------------------------
__global__ __launch_bounds__(128) void pool_final_kernel(
        const unsigned short* __restrict__ h,
        const int* __restrict__ batch,
        float* __restrict__ gcnt,
        float* __restrict__ pool,
        int* __restrict__ done,
        float* __restrict__ out) {
    int c = threadIdx.x;
    int n0 = blockIdx.x * POOL_CHUNK;
    int n1 = n0 + POOL_CHUNK;
    if (n1 > N_NODES) n1 = N_NODES;
    float run = 0.f, cnt = 0.f;
    int g = batch[n0];
    for (int n = n0; n < n1; n++) {
        int gn = batch[n];
        if (gn != g) {
            atomicAdd(&pool[g * OUT_CH + c], run);
            if (c == 0) atomicAdd(&gcnt[g], cnt);
            run = 0.f; cnt = 0.f; g = gn;
        }
        run += bf2f(h[(size_t)n * OUT_CH + c]);
        if (c == 0) cnt += 1.f;
    }
    atomicAdd(&pool[g * OUT_CH + c], run);
    if (c == 0) atomicAdd(&gcnt[g], cnt);

    __threadfence();
    __shared__ int lastb;
    if (c == 0) lastb = (atomicAdd(done, 1) == POOL_BLOCKS - 1) ? 1 : 0;
    __syncthreads();
    if (!lastb) return;

    __shared__ float gc[N_GRAPHS];
    if (c < N_GRAPHS) gc[c] = fmaxf(atomicAdd(&gcnt[c], 0.f), 1.0f);
    __syncthreads();
    for (int gg = 0; gg < N_GRAPHS; gg++) {
        float pv = atomicAdd(&pool[gg * OUT_CH + c], 0.f);
        out[gg * OUT_CH + c] = pv / gc[gg];
    }
}

// ---------------------------------------------------------------------------
extern "C" void kernel_launch(void* const* d_in, const int* in_sizes, int n_in,
                              void* d_out, int out_size, void* d_ws, size_t ws_size,
                              hipStream_t stream) {
    const float* x  = (const float*)d_in[0];
    const float* W1 = (const float*)d_in[1];
    const float* b1 = (const float*)d_in[2];
    const float* W2 = (const float*)d_in[3];
    const float* b2 = (const float*)d_in[4];
    const int*   ei = (const int*)d_in[5];
    const int*   batch = (const int*)d_in[6];
    float* out = (float*)d_out;

    // workspace layout (16B-aligned by construction)
    unsigned short* xb  = (unsigned short*)d_ws;                 // M_PAD*256 bf16
    unsigned short* h1b = xb  + (size_t)M_PAD * IN_CH;           // M_PAD*256 bf16
    unsigned short* hBb = h1b + (size_t)M_PAD * HID;             // M_PAD*256 bf16
    unsigned short* h2b = hBb + (size_t)M_PAD * HID;             // M_PAD*128 bf16
    unsigned short* w1t = h2b + (size_t)M_PAD * OUT_CH;          // 256*256
    unsigned short* w2t = w1t + HID * IN_CH;                     // 128*256
    unsigned short* hcb = xb;   // agg2 bf16 out aliases xb (dead after gemm1)
    float* dinv   = (float*)(w2t + OUT_CH * HID);                // 50000
    float* invdeg = dinv + N_NODES;                              // 50000
    int*   rl     = (int*)(invdeg + N_NODES);                    // 50001 (pad 50016)
    int2*  edge2  = (int2*)(rl + 50016);                         // 800000 int2
    int*   cnt    = (int*)(edge2 + N_EDGES);                     // 50000 (memset)
    int*   fillp  = cnt + N_NODES;                               // 50000 (zeroed in scan_a)
    float* gcnt   = (float*)(fillp + N_NODES);                   // 64   } zeroed in
    float* pool   = gcnt + N_GRAPHS;                             // 8192 } scanb blk384
    int*   done   = (int*)(pool + N_GRAPHS * OUT_CH);            // 1    }
    int*   blocksum = done + 4;                                  // 256
    int*   blockoff = blocksum + 256;                            // 256

    hipMemsetAsync(cnt, 0, (size_t)N_NODES * 4, stream);

    // A: histogram + x convert (independent, one launch)
    count_cvtx_kernel<<<COUNT_BLOCKS + CVTX_BLOCKS, 256, 0, stream>>>(ei, cnt, x, xb);
    // scan phase (also zeroes fillp)
    scan_a_kernel<<<SCAN_BLOCKS, 256, 0, stream>>>(cnt, rl, blocksum, dinv, invdeg, fillp);
    // weight convert + blocksum scan + zero gcnt/pool/done
    scanb_cvtw_kernel<<<385, 256, 0, stream>>>(blocksum, blockoff, W1, W2, w1t, w2t, gcnt);
    // B: gemm1 tiles + CSR fill (both depend only on the scans, one launch)
    fill_gemm1_kernel<<<GEMM1_BLOCKS + COUNT_BLOCKS, 256, 0, stream>>>(
        ei, rl, blockoff, fillp, edge2, dinv, xb, w1t, h1b);
    // conv1 aggregate (+ELU)
    agg1_kernel<<<(N_NODES + 3) / 4, 256, 0, stream>>>(h1b, b1, rl, blockoff,
                                                       edge2, invdeg, hBb);
    // conv2
    dim3 g2(M_PAD / 128, OUT_CH / 128);
    gemm_mfma_kernel<<<g2, 256, 0, stream>>>(hBb, w2t, h2b, OUT_CH);
    agg2_kernel<<<(N_NODES + 3) / 4, 256, 0, stream>>>(h2b, b2, rl, blockoff,
                                                       edge2, invdeg, hcb);
    // mean pool + final division (last-block reduction)
    pool_final_kernel<<<POOL_BLOCKS, 128, 0, stream>>>(hcb, batch, gcnt, pool, done, out);
}

// Round 12
// 310.441 us; speedup vs baseline: 1.2828x; 1.2828x over previous
//
#include <hip/hip_runtime.h>
#include <hip/hip_bf16.h>

#define N_NODES 50000
#define N_EDGES 800000
#define IN_CH 256
#define HID 256
#define OUT_CH 128
#define N_GRAPHS 64
#define SCAN_BLOCKS 196     // ceil(50001/256)
#define M_PAD 50048         // 391 * 128
#define POOL_CHUNK 32
#define POOL_BLOCKS ((N_NODES + POOL_CHUNK - 1) / POOL_CHUNK)   // 1563
#define COUNT_BLOCKS 3125   // N_EDGES / 256
#define CVTX_BLOCKS  12512  // M_PAD*64 / 256
#define GEMM1_BLOCKS 782    // 391 * 2

typedef __bf16 bf16x8 __attribute__((ext_vector_type(8)));
typedef float f32x4 __attribute__((ext_vector_type(4)));

// bf16 <-> f32 helpers (RNE on pack)
__device__ __forceinline__ float bf2f(unsigned short u) {
    union { unsigned int i; float f; } x; x.i = ((unsigned int)u) << 16; return x.f;
}
__device__ __forceinline__ unsigned short f2bf(float f) {
    union { float f; unsigned int i; } x; x.f = f;
    unsigned int r = x.i + 0x7FFFu + ((x.i >> 16) & 1u);
    return (unsigned short)(r >> 16);
}

__device__ __forceinline__ void load16(const void* g, void* l) {
    __builtin_amdgcn_global_load_lds(
        (const __attribute__((address_space(1))) void*)g,
        (__attribute__((address_space(3))) void*)l, 16, 0, 0);
}

// final rowptr = block-local exclusive + per-256-chunk offset
__device__ __forceinline__ int rp(const int* __restrict__ rl,
                                  const int* __restrict__ boff, int i) {
    return rl[i] + boff[i >> 8];
}

// ---------------------------------------------------------------------------
// Launch A: histogram of dst (blocks 0..3124) + x f32->bf16 padded convert
// (blocks 3125..15636). Independent subgraphs overlapped in one dispatch.
// ---------------------------------------------------------------------------
__global__ __launch_bounds__(256) void count_cvtx_kernel(const int* __restrict__ ei,
                                                         int* __restrict__ cnt,
                                                         const float* __restrict__ x,
                                                         unsigned short* __restrict__ xb) {
    int b = blockIdx.x;
    if (b < COUNT_BLOCKS) {
        int e = b * 256 + threadIdx.x;
        atomicAdd(&cnt[ei[N_EDGES + e]], 1);
        return;
    }
    int i = (b - COUNT_BLOCKS) * 256 + threadIdx.x;    // float4 index
    ushort4 o;
    if (i < N_NODES * (IN_CH / 4)) {
        float4 v = ((const float4*)x)[i];
        o.x = f2bf(v.x); o.y = f2bf(v.y); o.z = f2bf(v.z); o.w = f2bf(v.w);
    } else {
        o = make_ushort4(0, 0, 0, 0);
    }
    ((ushort4*)xb)[i] = o;
}

// ---------------------------------------------------------------------------
// scan_a: block-local exclusive scan; emits dinv/invdeg; zeroes fillp.
// ---------------------------------------------------------------------------
__global__ __launch_bounds__(256) void scan_a_kernel(const int* __restrict__ cnt,
                                                     int* __restrict__ rl,
                                                     int* __restrict__ blocksum,
                                                     float* __restrict__ dinv,
                                                     float* __restrict__ invdeg,
                                                     int* __restrict__ fillp) {
    __shared__ int tmp[256];
    int t = threadIdx.x;
    int i = blockIdx.x * 256 + t;
    int v = (i < N_NODES) ? cnt[i] : 0;
    int x = v;
    tmp[t] = x;
    __syncthreads();
#pragma unroll
    for (int off = 1; off < 256; off <<= 1) {
        int y = (t >= off) ? tmp[t - off] : 0;
        __syncthreads();
        x += y;
        tmp[t] = x;
        __syncthreads();
    }
    if (i <= N_NODES) rl[i] = x - v;
    if (i < N_NODES) {
        float d = (float)v + 1.0f;         // +1 self loop
        dinv[i] = rsqrtf(d);
        invdeg[i] = 1.0f / d;
        fillp[i] = 0;
    }
    if (t == 255) blocksum[blockIdx.x] = x;
}

// ---------------------------------------------------------------------------
// blocks 0..383: W1/W2 f32 -> bf16 transposed [N][K].
// block 384: scan of block sums -> blockoff, plus zero gcnt/pool.
// ---------------------------------------------------------------------------
__global__ __launch_bounds__(256) void scanb_cvtw_kernel(
        const int* __restrict__ blocksum, int* __restrict__ blockoff,
        const float* __restrict__ W1, const float* __restrict__ W2,
        unsigned short* __restrict__ w1t, unsigned short* __restrict__ w2t,
        float* __restrict__ zbase /* gcnt(64)+pool(8192) */) {
    int t = threadIdx.x;
    if (blockIdx.x < 384) {
        int i = blockIdx.x * 256 + t;                 // 0 .. 98303
        if (i < HID * IN_CH) {                        // W1t[n][k] = W1[k][n]
            int n = i >> 8, k = i & 255;
            w1t[i] = f2bf(W1[k * HID + n]);
        } else {                                      // W2t[n][k] = W2[k][n]
            int j = i - HID * IN_CH;
            int n = j >> 8, k = j & 255;
            w2t[j] = f2bf(W2[k * OUT_CH + n]);
        }
        return;
    }
    for (int i = t; i < N_GRAPHS + N_GRAPHS * OUT_CH; i += 256)
        zbase[i] = 0.f;
    __shared__ int tmp[256];
    int v = (t < SCAN_BLOCKS) ? blocksum[t] : 0;
    int x = v;
    tmp[t] = x;
    __syncthreads();
#pragma unroll
    for (int off = 1; off < 256; off <<= 1) {
        int y = (t >= off) ? tmp[t - off] : 0;
        __syncthreads();
        x += y;
        tmp[t] = x;
        __syncthreads();
    }
    if (t < SCAN_BLOCKS) blockoff[t] = x - v;
}

// ---------------------------------------------------------------------------
// GEMM tile body (128x128, 4 waves 2x2, 4x4 mfma_f32_16x16x32_bf16,
// global_load_lds width=16 staging, XOR-swizzled LDS chunks).
// ---------------------------------------------------------------------------
__device__ __forceinline__ void gemm_body(const unsigned short* __restrict__ A,
                                          const unsigned short* __restrict__ Bt,
                                          unsigned short* __restrict__ C,
                                          int N, int bxx, int byy, char* As, char* Bs) {
    const int K = 256;
    int tid = threadIdx.x;
    int bm = bxx * 128;
    int bn = byy * 128;
    int lane = tid & 63, wave = tid >> 6;
    int lane15 = lane & 15, quad = lane >> 4;
    int wm0 = (wave >> 1) << 6;
    int wn0 = (wave & 1) << 6;

    int s1 = tid, s2 = tid + 256;
    int r1 = s1 >> 2, q1 = (s1 & 3) ^ ((r1 >> 1) & 3);
    int r2 = s2 >> 2, q2 = (s2 & 3) ^ ((r2 >> 1) & 3);
    const char* gA1 = (const char*)(A + (size_t)(bm + r1) * K) + (q1 << 4);
    const char* gA2 = (const char*)(A + (size_t)(bm + r2) * K) + (q2 << 4);
    const char* gB1 = (const char*)(Bt + (size_t)(bn + r1) * K) + (q1 << 4);
    const char* gB2 = (const char*)(Bt + (size_t)(bn + r2) * K) + (q2 << 4);
    char* lA1 = As + (wave << 10);
    char* lA2 = As + 4096 + (wave << 10);
    char* lB1 = Bs + (wave << 10);
    char* lB2 = Bs + 4096 + (wave << 10);

    int swm = (lane15 >> 1) & 3;
    f32x4 acc[4][4];
#pragma unroll
    for (int mt = 0; mt < 4; mt++)
#pragma unroll
        for (int nt = 0; nt < 4; nt++)
            acc[mt][nt] = (f32x4){0.f, 0.f, 0.f, 0.f};

    for (int k0 = 0; k0 < K; k0 += 32) {
        __syncthreads();
        load16(gA1 + (k0 << 1), lA1);
        load16(gA2 + (k0 << 1), lA2);
        load16(gB1 + (k0 << 1), lB1);
        load16(gB2 + (k0 << 1), lB2);
        __syncthreads();
        bf16x8 af[4], bfr[4];
#pragma unroll
        for (int t = 0; t < 4; t++) {
            int ra = wm0 + t * 16 + lane15;
            af[t] = *(const bf16x8*)(As + ra * 64 + ((quad ^ swm) << 4));
            int rb = wn0 + t * 16 + lane15;
            bfr[t] = *(const bf16x8*)(Bs + rb * 64 + ((quad ^ swm) << 4));
        }
#pragma unroll
        for (int mt = 0; mt < 4; mt++)
#pragma unroll
            for (int nt = 0; nt < 4; nt++)
                acc[mt][nt] = __builtin_amdgcn_mfma_f32_16x16x32_bf16(
                    af[mt], bfr[nt], acc[mt][nt], 0, 0, 0);
    }

#pragma unroll
    for (int mt = 0; mt < 4; mt++) {
        int rowb = bm + wm0 + mt * 16 + quad * 4;
#pragma unroll
        for (int nt = 0; nt < 4; nt++) {
            int col = bn + wn0 + nt * 16 + lane15;
            f32x4 a = acc[mt][nt];
            C[(size_t)(rowb + 0) * N + col] = f2bf(a[0]);
            C[(size_t)(rowb + 1) * N + col] = f2bf(a[1]);
            C[(size_t)(rowb + 2) * N + col] = f2bf(a[2]);
            C[(size_t)(rowb + 3) * N + col] = f2bf(a[3]);
        }
    }
}

// Launch B: gemm1 tiles (blocks 0..781) + CSR fill (rest); both depend only
// on the scans. gemm blocks first so MFMA work starts immediately.
__global__ __launch_bounds__(256) void fill_gemm1_kernel(
        const int* __restrict__ ei,
        const int* __restrict__ rl,
        const int* __restrict__ boff,
        int* __restrict__ fillp,
        int2* __restrict__ edge2,
        const float* __restrict__ dinv,
        const unsigned short* __restrict__ xb,
        const unsigned short* __restrict__ w1t,
        unsigned short* __restrict__ h1b) {
    __shared__ char As[8192];
    __shared__ char Bs[8192];
    int b = blockIdx.x;
    if (b < GEMM1_BLOCKS) {
        gemm_body(xb, w1t, h1b, HID, b % 391, b / 391, As, Bs);
        return;
    }
    int e = (b - GEMM1_BLOCKS) * 256 + threadIdx.x;
    if (e >= N_EDGES) return;
    int s = ei[e];
    int d = ei[N_EDGES + e];
    int p = rp(rl, boff, d) + atomicAdd(&fillp[d], 1);
    float w = dinv[s] * dinv[d];
    edge2[p] = make_int2(s, __float_as_int(w));
}

// standalone gemm for conv2
__global__ __launch_bounds__(256) void gemm_mfma_kernel(
        const unsigned short* __restrict__ A,
        const unsigned short* __restrict__ Bt,
        unsigned short* __restrict__ C,
        int N) {
    __shared__ char As[8192];
    __shared__ char Bs[8192];
    gemm_body(A, Bt, C, N, blockIdx.x, blockIdx.y, As, Bs);
}

// ---------------------------------------------------------------------------
// GCN aggregation, 256ch (conv1): wave/node, lane = 4ch, bf16 ushort4
// gathers (512B/wave — measured better than 2x256B planar), 8-edge unroll,
// f32 accumulate, ELU, bf16 output.
// ---------------------------------------------------------------------------
#define ACC4(V, W) \
    acc.x += bf2f(V.x) * W; acc.y += bf2f(V.y) * W; \
    acc.z += bf2f(V.z) * W; acc.w += bf2f(V.w) * W;

__global__ __launch_bounds__(256) void agg1_kernel(const unsigned short* __restrict__ h,
                                                   const float* __restrict__ bias,
                                                   const int* __restrict__ rl,
                                                   const int* __restrict__ boff,
                                                   const int2* __restrict__ edge2,
                                                   const float* __restrict__ invdeg,
                                                   unsigned short* __restrict__ out) {
    int node = blockIdx.x * 4 + (threadIdx.x >> 6);
    if (node >= N_NODES) return;
    int lane = threadIdx.x & 63;
    const ushort4* h4 = (const ushort4*)h;
    float id = invdeg[node];
    ushort4 sv = h4[(size_t)node * 64 + lane];
    float4 acc = make_float4(bf2f(sv.x) * id, bf2f(sv.y) * id,
                             bf2f(sv.z) * id, bf2f(sv.w) * id);
    int e0 = rp(rl, boff, node);
    int e1 = rp(rl, boff, node + 1);
    int e = e0;
    for (; e + 7 < e1; e += 8) {
        int2 ed[8];
        ushort4 v[8];
#pragma unroll
        for (int j = 0; j < 8; j++) ed[j] = edge2[e + j];
#pragma unroll
        for (int j = 0; j < 8; j++) v[j] = h4[(size_t)ed[j].x * 64 + lane];
#pragma unroll
        for (int j = 0; j < 8; j++) {
            float w = __int_as_float(ed[j].y);
            ACC4(v[j], w);
        }
    }
    for (; e + 3 < e1; e += 4) {
        int2 ed[4];
        ushort4 v[4];
#pragma unroll
        for (int j = 0; j < 4; j++) ed[j] = edge2[e + j];
#pragma unroll
        for (int j = 0; j < 4; j++) v[j] = h4[(size_t)ed[j].x * 64 + lane];
#pragma unroll
        for (int j = 0; j < 4; j++) {
            float w = __int_as_float(ed[j].y);
            ACC4(v[j], w);
        }
    }
    for (; e < e1; e++) {
        int2 ed0 = edge2[e];
        float w0 = __int_as_float(ed0.y);
        ushort4 v0 = h4[(size_t)ed0.x * 64 + lane];
        ACC4(v0, w0);
    }
    float4 bb = ((const float4*)bias)[lane];
    acc.x += bb.x; acc.y += bb.y; acc.z += bb.z; acc.w += bb.w;
    acc.x = acc.x > 0.f ? acc.x : expm1f(acc.x);
    acc.y = acc.y > 0.f ? acc.y : expm1f(acc.y);
    acc.z = acc.z > 0.f ? acc.z : expm1f(acc.z);
    acc.w = acc.w > 0.f ? acc.w : expm1f(acc.w);
    ushort4 o;
    o.x = f2bf(acc.x); o.y = f2bf(acc.y); o.z = f2bf(acc.z); o.w = f2bf(acc.w);
    ((ushort4*)out)[(size_t)node * 64 + lane] = o;
}

// 128ch (conv2): wave/node, lane = 2ch, 8-edge unroll, bf16 output.
#define ACC2(V, W) \
    acc.x += bf2f(V.x) * W; acc.y += bf2f(V.y) * W;

__global__ __launch_bounds__(256) void agg2_kernel(const unsigned short* __restrict__ h,
                                                   const float* __restrict__ bias,
                                                   const int* __restrict__ rl,
                                                   const int* __restrict__ boff,
                                                   const int2* __restrict__ edge2,
                                                   const float* __restrict__ invdeg,
                                                   unsigned short* __restrict__ out) {
    int node = blockIdx.x * 4 + (threadIdx.x >> 6);
    if (node >= N_NODES) return;
    int lane = threadIdx.x & 63;
    const ushort2* h2 = (const ushort2*)h;
    float id = invdeg[node];
    ushort2 sv = h2[(size_t)node * 64 + lane];
    float2 acc = make_float2(bf2f(sv.x) * id, bf2f(sv.y) * id);
    int e0 = rp(rl, boff, node);
    int e1 = rp(rl, boff, node + 1);
    int e = e0;
    for (; e + 7 < e1; e += 8) {
        int2 ed[8];
        ushort2 v[8];
#pragma unroll
        for (int j = 0; j < 8; j++) ed[j] = edge2[e + j];
#pragma unroll
        for (int j = 0; j < 8; j++) v[j] = h2[(size_t)ed[j].x * 64 + lane];
#pragma unroll
        for (int j = 0; j < 8; j++) {
            float w = __int_as_float(ed[j].y);
            ACC2(v[j], w);
        }
    }
    for (; e + 3 < e1; e += 4) {
        int2 ed[4];
        ushort2 v[4];
#pragma unroll
        for (int j = 0; j < 4; j++) ed[j] = edge2[e + j];
#pragma unroll
        for (int j = 0; j < 4; j++) v[j] = h2[(size_t)ed[j].x * 64 + lane];
#pragma unroll
        for (int j = 0; j < 4; j++) {
            float w = __int_as_float(ed[j].y);
            ACC2(v[j], w);
        }
    }
    for (; e < e1; e++) {
        int2 ed0 = edge2[e];
        float w0 = __int_as_float(ed0.y);
        ushort2 v0 = h2[(size_t)ed0.x * 64 + lane];
        ACC2(v0, w0);
    }
    float2 bb = ((const float2*)bias)[lane];
    acc.x += bb.x; acc.y += bb.y;
    ushort2 o;
    o.x = f2bf(acc.x); o.y = f2bf(acc.y);
    ((ushort2*)out)[(size_t)node * 64 + lane] = o;
}

// ---------------------------------------------------------------------------
// Global mean pool over sorted batch (bf16 input): 32-node chunks.
// Plain two-kernel tail (fused last-block version measured 107 us due to
// per-block __threadfence — do NOT re-fuse).
// ---------------------------------------------------------------------------
__global__ __launch_bounds__(128) void pool_kernel(const unsigned short* __restrict__ h,
                                                   const int* __restrict__ batch,
                                                   float* __restrict__ pool,
                                                   float* __restrict__ gcnt) {
    int c = threadIdx.x;
    int n0 = blockIdx.x * POOL_CHUNK;
    int n1 = n0 + POOL_CHUNK;
    if (n1 > N_NODES) n1 = N_NODES;
    if (n0 >= N_NODES) return;
    float run = 0.f, cnt = 0.f;
    int g = batch[n0];
    for (int n = n0; n < n1; n++) {
        int gn = batch[n];
        if (gn != g) {
            atomicAdd(&pool[g * OUT_CH + c], run);
            if (c == 0) atomicAdd(&gcnt[g], cnt);
            run = 0.f; cnt = 0.f; g = gn;
        }
        run += bf2f(h[(size_t)n * OUT_CH + c]);
        if (c == 0) cnt += 1.f;
    }
    atomicAdd(&pool[g * OUT_CH + c], run);
    if (c == 0) atomicAdd(&gcnt[g], cnt);
}

__global__ __launch_bounds__(256) void final_kernel(const float* __restrict__ pool,
                                                    const float* __restrict__ gcnt,
                                                    float* __restrict__ out) {
    int i = blockIdx.x * 256 + threadIdx.x;
    if (i < N_GRAPHS * OUT_CH)
        out[i] = pool[i] / fmaxf(gcnt[i >> 7], 1.0f);
}

// ---------------------------------------------------------------------------
extern "C" void kernel_launch(void* const* d_in, const int* in_sizes, int n_in,
                              void* d_out, int out_size, void* d_ws, size_t ws_size,
                              hipStream_t stream) {
    const float* x  = (const float*)d_in[0];
    const float* W1 = (const float*)d_in[1];
    const float* b1 = (const float*)d_in[2];
    const float* W2 = (const float*)d_in[3];
    const float* b2 = (const float*)d_in[4];
    const int*   ei = (const int*)d_in[5];
    const int*   batch = (const int*)d_in[6];
    float* out = (float*)d_out;

    // workspace layout (16B-aligned by construction)
    unsigned short* xb  = (unsigned short*)d_ws;                 // M_PAD*256 bf16
    unsigned short* h1b = xb  + (size_t)M_PAD * IN_CH;           // M_PAD*256 bf16
    unsigned short* hBb = h1b + (size_t)M_PAD * HID;             // M_PAD*256 bf16
    unsigned short* h2b = hBb + (size_t)M_PAD * HID;             // M_PAD*128 bf16
    unsigned short* w1t = h2b + (size_t)M_PAD * OUT_CH;          // 256*256
    unsigned short* w2t = w1t + HID * IN_CH;                     // 128*256
    unsigned short* hcb = xb;   // agg2 bf16 out aliases xb (dead after gemm1)
    float* dinv   = (float*)(w2t + OUT_CH * HID);                // 50000
    float* invdeg = dinv + N_NODES;                              // 50000
    int*   rl     = (int*)(invdeg + N_NODES);                    // 50001 (pad 50016)
    int2*  edge2  = (int2*)(rl + 50016);                         // 800000 int2
    int*   cnt    = (int*)(edge2 + N_EDGES);                     // 50000 (memset)
    int*   fillp  = cnt + N_NODES;                               // 50000 (zeroed in scan_a)
    float* gcnt   = (float*)(fillp + N_NODES);                   // 64   } zeroed in
    float* pool   = gcnt + N_GRAPHS;                             // 8192 } scanb blk384
    int*   blocksum = (int*)(pool + N_GRAPHS * OUT_CH);          // 256
    int*   blockoff = blocksum + 256;                            // 256

    hipMemsetAsync(cnt, 0, (size_t)N_NODES * 4, stream);

    // A: histogram + x convert (independent, one launch)
    count_cvtx_kernel<<<COUNT_BLOCKS + CVTX_BLOCKS, 256, 0, stream>>>(ei, cnt, x, xb);
    // scan phase (also zeroes fillp)
    scan_a_kernel<<<SCAN_BLOCKS, 256, 0, stream>>>(cnt, rl, blocksum, dinv, invdeg, fillp);
    // weight convert + blocksum scan + zero gcnt/pool
    scanb_cvtw_kernel<<<385, 256, 0, stream>>>(blocksum, blockoff, W1, W2, w1t, w2t, gcnt);
    // B: gemm1 tiles + CSR fill (one launch)
    fill_gemm1_kernel<<<GEMM1_BLOCKS + COUNT_BLOCKS, 256, 0, stream>>>(
        ei, rl, blockoff, fillp, edge2, dinv, xb, w1t, h1b);
    // conv1 aggregate (+ELU)
    agg1_kernel<<<(N_NODES + 3) / 4, 256, 0, stream>>>(h1b, b1, rl, blockoff,
                                                       edge2, invdeg, hBb);
    // conv2
    dim3 g2(M_PAD / 128, OUT_CH / 128);
    gemm_mfma_kernel<<<g2, 256, 0, stream>>>(hBb, w2t, h2b, OUT_CH);
    agg2_kernel<<<(N_NODES + 3) / 4, 256, 0, stream>>>(h2b, b2, rl, blockoff,
                                                       edge2, invdeg, hcb);
    // mean pool (plain) + final division
    pool_kernel<<<POOL_BLOCKS, 128, 0, stream>>>(hcb, batch, pool, gcnt);
    final_kernel<<<(N_GRAPHS * OUT_CH + 255) / 256, 256, 0, stream>>>(pool, gcnt, out);
}